// Round 15
// baseline (27.227 us; speedup 1.0000x reference)
//
#include <hip/hip_runtime.h>

// out[n,k] = sum_{i,j} x[n,i] * W[k,i,j] * x[n,j]   (N=262144 rows, D=32)
// R15 vs R14 (27.1us): FORCE THE 64-REG OCCUPANCY STEP. R13 counters showed
// latency-bound (MFMA busy 3.4us, VALU 8us, BW 21%, Occ 42.6%); R14 raised
// occupancy 16->24 waves/CU and gained 3us -- the only lever that has moved
// the plateau. R14's 1-tile state is ~56-60 total regs (ypk 16 + acc 16 AGPR
// + temps), just at the 64-reg granule: launch_bounds(512,8) forces <=64 ->
// 8 waves/SIMD = 32 waves/CU (100%); LDS 4 blocks x 33KiB = 132 <= 160 OK.
// Prep kernel widened to 66x256. K-loop math identical (absmax 0.25).
//
// Algorithm: symmetrized circular-diagonal GEMM. p = d*32+i, d=0..16,
// z[n,p] = x[n,i]*x[n,(i+d)&31], Wf[p,k] = W[k,i,j]+W[k,j,i] (d=0 diag,
// d=16 half), K = 528 = 33 MFMA steps of v_mfma_f32_32x32x16_f16.
// One-time prep kernel builds the f16 Wsym fragment table in d_ws.

typedef _Float16 f16x2 __attribute__((ext_vector_type(2)));
typedef _Float16 f16x4 __attribute__((ext_vector_type(4)));
typedef _Float16 f16x8 __attribute__((ext_vector_type(8)));
typedef float    f32x16 __attribute__((ext_vector_type(16)));

static __device__ __forceinline__ unsigned int pk2_f16(float lo, float hi) {
    return __builtin_bit_cast(unsigned int, __builtin_amdgcn_cvt_pkrtz(lo, hi));
}
static __device__ __forceinline__ f16x2 u2h(unsigned int u) {
    return __builtin_bit_cast(f16x2, u);
}
static __device__ __forceinline__ unsigned short f16b(float f) {
    _Float16 h = (_Float16)f;
    return __builtin_bit_cast(unsigned short, h);
}

// ---- one-time prep: symmetrized fragment table (16896 f16 = 33 KiB) ----
// bt[(n*64+l)*8+b] = f16( W[k,i,j]+W[k,j,i] ),  k=l&31, i=q*16+(l>>5)*8+b,
// j=(i+d)&31, d=(n==32)?16:n>>1, q=(n==32)?0:n&1;  d==0 -> W[k,i,i].
__global__ __launch_bounds__(256)
void prep_btab_sym(const float* __restrict__ W, unsigned short* __restrict__ bt) {
    int idx = blockIdx.x * 256 + threadIdx.x;   // 0..16895 (grid = 66)
    int n = idx >> 9;
    int e = idx & 511;
    int l = e >> 3, b = e & 7;
    int d = (n == 32) ? 16 : (n >> 1);
    int q = (n == 32) ? 0  : (n & 1);
    int i = q * 16 + ((l >> 5) << 3) + b;
    int j = (i + d) & 31;
    const float* Wk = W + (l & 31) * 1024;
    float v = (d == 0) ? Wk[i * 32 + i] : Wk[i * 32 + j] + Wk[j * 32 + i];
    bt[idx] = f16b(v);
}

__global__ __launch_bounds__(512, 8)
void quadform_kernel(const float* __restrict__ x,
                     const unsigned short* __restrict__ bt_ws,
                     float* __restrict__ out) {
    __shared__ __align__(16) unsigned short btab[33 * 64 * 8];   // 33 KiB

    const int tid  = threadIdx.x;
    const int lane = tid & 63;
    const int wave = tid >> 6;
    const int hi   = lane >> 5;
    const int rl   = lane & 31;
    const long wrow = (long)blockIdx.x * 256 + wave * 32;   // 1 tile (32 rows)/wave

    // ---- x row load issued first (hides under btab copy) ----
    const float4* xr = (const float4*)(x + (wrow + rl) * 32);

    // ---- coalesced copy ws -> LDS (2112 uint4) ----
    {
        const uint4* src = (const uint4*)bt_ws;
        uint4* dst = (uint4*)btab;
        #pragma unroll
        for (int c = 0; c < 5; ++c) {
            int idx = c * 512 + tid;
            if (idx < 2112) dst[idx] = src[idx];
        }
    }

    // ---- pack row to f16 pairs, pre-rotate by hi*4 (static indices) ----
    unsigned int ypk[16];
    {
        unsigned int xpk[16];
        #pragma unroll
        for (int c = 0; c < 8; ++c) {
            float4 v = xr[c];
            xpk[2 * c + 0] = pk2_f16(v.x, v.y);
            xpk[2 * c + 1] = pk2_f16(v.z, v.w);
        }
        #pragma unroll
        for (int c = 0; c < 16; ++c)
            ypk[c] = hi ? xpk[(c + 4) & 15] : xpk[c];
    }

    f32x16 acc;
    #pragma unroll
    for (int e = 0; e < 16; ++e) acc[e] = 0.0f;

    __syncthreads();

    // ---- K loop: 33 steps (17 circular diagonals), fully unrolled, SSA ----
    #pragma unroll
    for (int s = 0; s < 33; ++s) {
        const int d   = (s == 32) ? 16 : (s >> 1);
        const int q8  = ((s == 32) ? 0 : (s & 1)) * 8;
        const int dh  = d >> 1;
        const bool od = (d & 1) != 0;
        f16x8 bfrag = *(const f16x8*)(&btab[(s * 64 + lane) * 8]);

        f16x2 b0 = od ? u2h(__builtin_amdgcn_perm(ypk[(q8 + 0 + dh + 1) & 15], ypk[(q8 + 0 + dh) & 15], 0x05040302u)) : u2h(ypk[(q8 + 0 + dh) & 15]);
        f16x2 b1 = od ? u2h(__builtin_amdgcn_perm(ypk[(q8 + 1 + dh + 1) & 15], ypk[(q8 + 1 + dh) & 15], 0x05040302u)) : u2h(ypk[(q8 + 1 + dh) & 15]);
        f16x2 b2 = od ? u2h(__builtin_amdgcn_perm(ypk[(q8 + 2 + dh + 1) & 15], ypk[(q8 + 2 + dh) & 15], 0x05040302u)) : u2h(ypk[(q8 + 2 + dh) & 15]);
        f16x2 b3 = od ? u2h(__builtin_amdgcn_perm(ypk[(q8 + 3 + dh + 1) & 15], ypk[(q8 + 3 + dh) & 15], 0x05040302u)) : u2h(ypk[(q8 + 3 + dh) & 15]);
        f16x2 a0 = u2h(ypk[q8 + 0]) * b0;
        f16x2 a1 = u2h(ypk[q8 + 1]) * b1;
        f16x2 a2 = u2h(ypk[q8 + 2]) * b2;
        f16x2 a3 = u2h(ypk[q8 + 3]) * b3;
        f16x4 lo = __builtin_shufflevector(a0, a1, 0, 1, 2, 3);
        f16x4 hf = __builtin_shufflevector(a2, a3, 0, 1, 2, 3);
        f16x8 a  = __builtin_shufflevector(lo, hf, 0, 1, 2, 3, 4, 5, 6, 7);
        acc = __builtin_amdgcn_mfma_f32_32x32x16_f16(a, bfrag, acc, 0, 0, 0);
    }

    // ---- store: col = lane&31 (k), row = (e&3) + 8*(e>>2) + 4*hi ----
    #pragma unroll
    for (int e = 0; e < 16; ++e) {
        int row = (e & 3) + 8 * (e >> 2) + 4 * hi;
        out[(wrow + row) * 32 + rl] = acc[e];
    }
}

extern "C" void kernel_launch(void* const* d_in, const int* in_sizes, int n_in,
                              void* d_out, int out_size, void* d_ws, size_t ws_size,
                              hipStream_t stream) {
    const float* x = (const float*)d_in[0];
    const float* W = (const float*)d_in[1];
    float* out = (float*)d_out;
    unsigned short* bt = (unsigned short*)d_ws;    // 33 KiB table

    prep_btab_sym<<<66, 256, 0, stream>>>(W, bt);
    int nrows = in_sizes[0] / 32;          // 262144
    int grid  = nrows / 256;               // 1024 blocks x 512 thr (1 tile/wave)
    quadform_kernel<<<grid, 512, 0, stream>>>(x, bt, out);
}

// Round 16
// 26.746 us; speedup vs baseline: 1.0180x; 1.0180x over previous
//
#include <hip/hip_runtime.h>

// out[n,k] = sum_{i,j} x[n,i] * W[k,i,j] * x[n,j]   (N=262144 rows, D=32)
// R16 vs R15 (27.2us): occupancy saturated (R14 (512,6) == R15 (512,8) ==
// 27.1/27.2 -> allocator already at <=64 regs, ~32 waves/CU). Not BW-bound
// (1.85 TB/s = 23% achievable). Remaining removable overhead attacked here:
//  1) prep kernel: was a scattered gather (every 4B load its own cache line,
//     ~2-4us serial graph leg). Now: 32 blocks (one per k) stage W_k (4KB)
//     into LDS coalesced, gather from LDS, write 16B chunks.
//  2) epilogue: 16 stores folded onto ONE base + constant immediate offsets
//     (R7 disasm showed v_lshl_add_u64 chains per store) + nontemporal hint
//     (out is write-once; keep L2 for x/btab).
// Main structure/math byte-identical to R15 (absmax 0.25).
//
// Algorithm: symmetrized circular-diagonal GEMM. p = d*32+i, d=0..16,
// z[n,p] = x[n,i]*x[n,(i+d)&31], Wf[p,k] = W[k,i,j]+W[k,j,i] (d=0 diag,
// d=16 half), K = 528 = 33 MFMA steps of v_mfma_f32_32x32x16_f16.

typedef _Float16 f16x2 __attribute__((ext_vector_type(2)));
typedef _Float16 f16x4 __attribute__((ext_vector_type(4)));
typedef _Float16 f16x8 __attribute__((ext_vector_type(8)));
typedef float    f32x16 __attribute__((ext_vector_type(16)));

static __device__ __forceinline__ unsigned int pk2_f16(float lo, float hi) {
    return __builtin_bit_cast(unsigned int, __builtin_amdgcn_cvt_pkrtz(lo, hi));
}
static __device__ __forceinline__ f16x2 u2h(unsigned int u) {
    return __builtin_bit_cast(f16x2, u);
}
static __device__ __forceinline__ unsigned short f16b(float f) {
    _Float16 h = (_Float16)f;
    return __builtin_bit_cast(unsigned short, h);
}

// ---- prep v2: one block per k; stage W_k in LDS coalesced, then gather ----
// bt[(n*64+l)*8+b] = f16( Wsym ), k=l&31, i=q*16+(l>>5)*8+b, j=(i+d)&31,
// d=(n==32)?16:n>>1, q=(n==32)?0:n&1; d==0 -> W[k,i,i].
__global__ __launch_bounds__(256)
void prep_btab_sym(const float* __restrict__ W, unsigned short* __restrict__ bt) {
    __shared__ float Wlds[1024];                    // 4 KiB = W[k,:,:]
    const int k = blockIdx.x;                       // 0..31
    const int t = threadIdx.x;
    {   // coalesced stage: 256 thr x float4
        const float4* src = (const float4*)(W + k * 1024);
        ((float4*)Wlds)[t] = src[t];
    }
    __syncthreads();
    if (t < 66) {                                   // 33 n x 2 l-halves
        int n  = t >> 1;
        int lh = t & 1;                             // l = k + lh*32
        int d  = (n == 32) ? 16 : (n >> 1);
        int q  = (n == 32) ? 0  : (n & 1);
        unsigned short v[8];
        #pragma unroll
        for (int b = 0; b < 8; ++b) {
            int i = q * 16 + lh * 8 + b;
            int j = (i + d) & 31;
            float s = (d == 0) ? Wlds[i * 32 + i]
                               : Wlds[i * 32 + j] + Wlds[j * 32 + i];
            v[b] = f16b(s);
        }
        // 16B chunk at fragment (n, l=k+lh*32)
        uint4 pk;
        pk.x = (unsigned int)v[0] | ((unsigned int)v[1] << 16);
        pk.y = (unsigned int)v[2] | ((unsigned int)v[3] << 16);
        pk.z = (unsigned int)v[4] | ((unsigned int)v[5] << 16);
        pk.w = (unsigned int)v[6] | ((unsigned int)v[7] << 16);
        ((uint4*)bt)[n * 64 + k + lh * 32] = pk;
    }
}

__global__ __launch_bounds__(512, 8)
void quadform_kernel(const float* __restrict__ x,
                     const unsigned short* __restrict__ bt_ws,
                     float* __restrict__ out) {
    __shared__ __align__(16) unsigned short btab[33 * 64 * 8];   // 33 KiB

    const int tid  = threadIdx.x;
    const int lane = tid & 63;
    const int wave = tid >> 6;
    const int hi   = lane >> 5;
    const int rl   = lane & 31;
    const long wrow = (long)blockIdx.x * 256 + wave * 32;   // 1 tile (32 rows)/wave

    // ---- x row load issued first (hides under btab copy) ----
    const float4* xr = (const float4*)(x + (wrow + rl) * 32);

    // ---- coalesced copy ws -> LDS (2112 uint4) ----
    {
        const uint4* src = (const uint4*)bt_ws;
        uint4* dst = (uint4*)btab;
        #pragma unroll
        for (int c = 0; c < 5; ++c) {
            int idx = c * 512 + tid;
            if (idx < 2112) dst[idx] = src[idx];
        }
    }

    // ---- pack row to f16 pairs, pre-rotate by hi*4 (static indices) ----
    unsigned int ypk[16];
    {
        unsigned int xpk[16];
        #pragma unroll
        for (int c = 0; c < 8; ++c) {
            float4 v = xr[c];
            xpk[2 * c + 0] = pk2_f16(v.x, v.y);
            xpk[2 * c + 1] = pk2_f16(v.z, v.w);
        }
        #pragma unroll
        for (int c = 0; c < 16; ++c)
            ypk[c] = hi ? xpk[(c + 4) & 15] : xpk[c];
    }

    f32x16 acc;
    #pragma unroll
    for (int e = 0; e < 16; ++e) acc[e] = 0.0f;

    __syncthreads();

    // ---- K loop: 33 steps (17 circular diagonals), fully unrolled, SSA ----
    #pragma unroll
    for (int s = 0; s < 33; ++s) {
        const int d   = (s == 32) ? 16 : (s >> 1);
        const int q8  = ((s == 32) ? 0 : (s & 1)) * 8;
        const int dh  = d >> 1;
        const bool od = (d & 1) != 0;
        f16x8 bfrag = *(const f16x8*)(&btab[(s * 64 + lane) * 8]);

        f16x2 b0 = od ? u2h(__builtin_amdgcn_perm(ypk[(q8 + 0 + dh + 1) & 15], ypk[(q8 + 0 + dh) & 15], 0x05040302u)) : u2h(ypk[(q8 + 0 + dh) & 15]);
        f16x2 b1 = od ? u2h(__builtin_amdgcn_perm(ypk[(q8 + 1 + dh + 1) & 15], ypk[(q8 + 1 + dh) & 15], 0x05040302u)) : u2h(ypk[(q8 + 1 + dh) & 15]);
        f16x2 b2 = od ? u2h(__builtin_amdgcn_perm(ypk[(q8 + 2 + dh + 1) & 15], ypk[(q8 + 2 + dh) & 15], 0x05040302u)) : u2h(ypk[(q8 + 2 + dh) & 15]);
        f16x2 b3 = od ? u2h(__builtin_amdgcn_perm(ypk[(q8 + 3 + dh + 1) & 15], ypk[(q8 + 3 + dh) & 15], 0x05040302u)) : u2h(ypk[(q8 + 3 + dh) & 15]);
        f16x2 a0 = u2h(ypk[q8 + 0]) * b0;
        f16x2 a1 = u2h(ypk[q8 + 1]) * b1;
        f16x2 a2 = u2h(ypk[q8 + 2]) * b2;
        f16x2 a3 = u2h(ypk[q8 + 3]) * b3;
        f16x4 lo = __builtin_shufflevector(a0, a1, 0, 1, 2, 3);
        f16x4 hf = __builtin_shufflevector(a2, a3, 0, 1, 2, 3);
        f16x8 a  = __builtin_shufflevector(lo, hf, 0, 1, 2, 3, 4, 5, 6, 7);
        acc = __builtin_amdgcn_mfma_f32_32x32x16_f16(a, bfrag, acc, 0, 0, 0);
    }

    // ---- store: one base, 16 constant-offset nontemporal stores ----
    // col = rl (k), rows = 4*hi + (e&3) + 8*(e>>2)
    float* ob = out + (wrow + 4 * hi) * 32 + rl;
    #pragma unroll
    for (int e = 0; e < 16; ++e)
        __builtin_nontemporal_store(acc[e], ob + (e & 3) * 32 + (e >> 2) * 256);
}

extern "C" void kernel_launch(void* const* d_in, const int* in_sizes, int n_in,
                              void* d_out, int out_size, void* d_ws, size_t ws_size,
                              hipStream_t stream) {
    const float* x = (const float*)d_in[0];
    const float* W = (const float*)d_in[1];
    float* out = (float*)d_out;
    unsigned short* bt = (unsigned short*)d_ws;    // 33 KiB table

    prep_btab_sym<<<32, 256, 0, stream>>>(W, bt);
    int nrows = in_sizes[0] / 32;          // 262144
    int grid  = nrows / 256;               // 1024 blocks x 512 thr (1 tile/wave)
    quadform_kernel<<<grid, 512, 0, stream>>>(x, bt, out);
}

// Round 17
// 22.835 us; speedup vs baseline: 1.1924x; 1.1713x over previous
//
#include <hip/hip_runtime.h>

// out[n,k] = sum_{i,j} x[n,i] * W[k,i,j] * x[n,j]   (N=262144 rows, D=32)
// R17 vs R16 (26.7us): attack the startup front (latency-bound, occupancy
// saturated at 32 waves/CU, BW 23%).
//  1) COALESCED x: 4 float4/thread, lane-consecutive 16B (8 lines/wave-instr
//     vs 32 for the old per-row strided loads); pack f16 in-register; stage
//     rows in LDS at 80B stride (write conflicts 2-way=free, reads ~4-way).
//     Per-block x line-touches drop 4x.
//  2) 1024-thr blocks (16 waves, 512 rows): halves table-copy count;
//     launch_bounds(1024,8) keeps 64-reg / 32 waves/CU. LDS 33+40=73.8KiB
//     -> 2 blocks/CU. Issue order: x loads -> btab loads -> stage -> barrier.
// K-loop / math / stores byte-identical to R16 (absmax 0.25).
//
// Algorithm: symmetrized circular-diagonal GEMM. p = d*32+i, d=0..16,
// z[n,p] = x[n,i]*x[n,(i+d)&31], Wf[p,k] = W[k,i,j]+W[k,j,i] (d=0 diag,
// d=16 half), K = 528 = 33 MFMA steps of v_mfma_f32_32x32x16_f16.

typedef _Float16 f16x2 __attribute__((ext_vector_type(2)));
typedef _Float16 f16x4 __attribute__((ext_vector_type(4)));
typedef _Float16 f16x8 __attribute__((ext_vector_type(8)));
typedef float    f32x16 __attribute__((ext_vector_type(16)));

static __device__ __forceinline__ unsigned int pk2_f16(float lo, float hi) {
    return __builtin_bit_cast(unsigned int, __builtin_amdgcn_cvt_pkrtz(lo, hi));
}
static __device__ __forceinline__ f16x2 u2h(unsigned int u) {
    return __builtin_bit_cast(f16x2, u);
}
static __device__ __forceinline__ unsigned short f16b(float f) {
    _Float16 h = (_Float16)f;
    return __builtin_bit_cast(unsigned short, h);
}

// ---- prep (R16): one block per k; stage W_k in LDS coalesced, gather ----
__global__ __launch_bounds__(256)
void prep_btab_sym(const float* __restrict__ W, unsigned short* __restrict__ bt) {
    __shared__ float Wlds[1024];                    // 4 KiB = W[k,:,:]
    const int k = blockIdx.x;                       // 0..31
    const int t = threadIdx.x;
    {
        const float4* src = (const float4*)(W + k * 1024);
        ((float4*)Wlds)[t] = src[t];
    }
    __syncthreads();
    if (t < 66) {                                   // 33 n x 2 l-halves
        int n  = t >> 1;
        int lh = t & 1;                             // l = k + lh*32
        int d  = (n == 32) ? 16 : (n >> 1);
        int q  = (n == 32) ? 0  : (n & 1);
        unsigned short v[8];
        #pragma unroll
        for (int b = 0; b < 8; ++b) {
            int i = q * 16 + lh * 8 + b;
            int j = (i + d) & 31;
            float s = (d == 0) ? Wlds[i * 32 + i]
                               : Wlds[i * 32 + j] + Wlds[j * 32 + i];
            v[b] = f16b(s);
        }
        uint4 pk;
        pk.x = (unsigned int)v[0] | ((unsigned int)v[1] << 16);
        pk.y = (unsigned int)v[2] | ((unsigned int)v[3] << 16);
        pk.z = (unsigned int)v[4] | ((unsigned int)v[5] << 16);
        pk.w = (unsigned int)v[6] | ((unsigned int)v[7] << 16);
        ((uint4*)bt)[n * 64 + k + lh * 32] = pk;
    }
}

#define XS 20   // u32 per staged row (16 used + 4 pad -> bank spread)

__global__ __launch_bounds__(1024, 8)
void quadform_kernel(const float* __restrict__ x,
                     const unsigned short* __restrict__ bt_ws,
                     float* __restrict__ out) {
    __shared__ __align__(16) unsigned short btab[33 * 64 * 8];   // 33792 B
    __shared__ __align__(16) unsigned int   xstage[512 * XS];    // 40960 B

    const int tid  = threadIdx.x;
    const int lane = tid & 63;
    const int wave = tid >> 6;
    const int hi   = lane >> 5;
    const int rl   = lane & 31;
    const long blockrow = (long)blockIdx.x * 512;
    const long wrow = blockrow + wave * 32;         // this wave's 32 rows

    // ---- 1) issue coalesced x loads (HBM, slow - first) ----
    const float4* xsrc = (const float4*)(x + blockrow * 32);
    float4 xg0 = xsrc[tid];
    float4 xg1 = xsrc[1024 + tid];
    float4 xg2 = xsrc[2048 + tid];
    float4 xg3 = xsrc[3072 + tid];

    // ---- 2) issue btab loads (L2, fast) ----
    const uint4* bsrc = (const uint4*)bt_ws;
    uint4 b0 = bsrc[tid];
    uint4 b1 = bsrc[1024 + tid];
    uint4 b2;
    if (tid < 64) b2 = bsrc[2048 + tid];

    // ---- 3) pack + stage x (waits only on x loads) ----
    #pragma unroll
    for (int c = 0; c < 4; ++c) {
        float4 v = (c == 0) ? xg0 : (c == 1) ? xg1 : (c == 2) ? xg2 : xg3;
        int idx = c * 1024 + tid;                   // float4 index 0..4095
        int row = idx >> 3;                         // 8 float4 per row
        int sub = idx & 7;
        uint2 w2;
        w2.x = pk2_f16(v.x, v.y);
        w2.y = pk2_f16(v.z, v.w);
        *(uint2*)&xstage[row * XS + sub * 2] = w2;
    }
    // ---- 4) write btab ----
    {
        uint4* dst = (uint4*)btab;
        dst[tid]        = b0;
        dst[1024 + tid] = b1;
        if (tid < 64) dst[2048 + tid] = b2;
    }
    __syncthreads();

    // ---- read own row from stage, pre-rotate by hi*4 (static indices) ----
    unsigned int ypk[16];
    {
        unsigned int xpk[16];
        const unsigned int* xr = &xstage[(wave * 32 + rl) * XS];
        #pragma unroll
        for (int c = 0; c < 4; ++c) {
            uint4 v = *(const uint4*)(xr + c * 4);
            xpk[c * 4 + 0] = v.x;
            xpk[c * 4 + 1] = v.y;
            xpk[c * 4 + 2] = v.z;
            xpk[c * 4 + 3] = v.w;
        }
        #pragma unroll
        for (int c = 0; c < 16; ++c)
            ypk[c] = hi ? xpk[(c + 4) & 15] : xpk[c];
    }

    f32x16 acc;
    #pragma unroll
    for (int e = 0; e < 16; ++e) acc[e] = 0.0f;

    // ---- K loop: 33 steps (17 circular diagonals), fully unrolled, SSA ----
    #pragma unroll
    for (int s = 0; s < 33; ++s) {
        const int d   = (s == 32) ? 16 : (s >> 1);
        const int q8  = ((s == 32) ? 0 : (s & 1)) * 8;
        const int dh  = d >> 1;
        const bool od = (d & 1) != 0;
        f16x8 bfrag = *(const f16x8*)(&btab[(s * 64 + lane) * 8]);

        f16x2 b0 = od ? u2h(__builtin_amdgcn_perm(ypk[(q8 + 0 + dh + 1) & 15], ypk[(q8 + 0 + dh) & 15], 0x05040302u)) : u2h(ypk[(q8 + 0 + dh) & 15]);
        f16x2 b1 = od ? u2h(__builtin_amdgcn_perm(ypk[(q8 + 1 + dh + 1) & 15], ypk[(q8 + 1 + dh) & 15], 0x05040302u)) : u2h(ypk[(q8 + 1 + dh) & 15]);
        f16x2 b2 = od ? u2h(__builtin_amdgcn_perm(ypk[(q8 + 2 + dh + 1) & 15], ypk[(q8 + 2 + dh) & 15], 0x05040302u)) : u2h(ypk[(q8 + 2 + dh) & 15]);
        f16x2 b3 = od ? u2h(__builtin_amdgcn_perm(ypk[(q8 + 3 + dh + 1) & 15], ypk[(q8 + 3 + dh) & 15], 0x05040302u)) : u2h(ypk[(q8 + 3 + dh) & 15]);
        f16x2 a0 = u2h(ypk[q8 + 0]) * b0;
        f16x2 a1 = u2h(ypk[q8 + 1]) * b1;
        f16x2 a2 = u2h(ypk[q8 + 2]) * b2;
        f16x2 a3 = u2h(ypk[q8 + 3]) * b3;
        f16x4 lo = __builtin_shufflevector(a0, a1, 0, 1, 2, 3);
        f16x4 hf = __builtin_shufflevector(a2, a3, 0, 1, 2, 3);
        f16x8 a  = __builtin_shufflevector(lo, hf, 0, 1, 2, 3, 4, 5, 6, 7);
        acc = __builtin_amdgcn_mfma_f32_32x32x16_f16(a, bfrag, acc, 0, 0, 0);
    }

    // ---- store: one base, 16 constant-offset nontemporal stores ----
    float* ob = out + (wrow + 4 * hi) * 32 + rl;
    #pragma unroll
    for (int e = 0; e < 16; ++e)
        __builtin_nontemporal_store(acc[e], ob + (e & 3) * 32 + (e >> 2) * 256);
}

extern "C" void kernel_launch(void* const* d_in, const int* in_sizes, int n_in,
                              void* d_out, int out_size, void* d_ws, size_t ws_size,
                              hipStream_t stream) {
    const float* x = (const float*)d_in[0];
    const float* W = (const float*)d_in[1];
    float* out = (float*)d_out;
    unsigned short* bt = (unsigned short*)d_ws;    // 33 KiB table

    prep_btab_sym<<<32, 256, 0, stream>>>(W, bt);
    int nrows = in_sizes[0] / 32;          // 262144
    int grid  = nrows / 512;               // 512 blocks x 1024 thr
    quadform_kernel<<<grid, 1024, 0, stream>>>(x, bt, out);
}